// Round 24
// baseline (170.339 us; speedup 1.0000x reference)
//
#include <hip/hip_runtime.h>
#include <math.h>

#define HID 2048
#define NH 16
#define NKV 4
#define DH 128
#define BB 2
#define SS 2048
#define ROWS (BB*SS)     // 4096
#define NQKV 3072
#define KOFF 2048        // K block col offset in QKV
#define VOFF 2560        // V block col offset in QKV

typedef float f32x4 __attribute__((ext_vector_type(4)));
typedef float f32x16 __attribute__((ext_vector_type(16)));
typedef __bf16 bf16x8 __attribute__((ext_vector_type(8)));
typedef unsigned short ushortx8 __attribute__((ext_vector_type(8)));
typedef unsigned short ushortx4 __attribute__((ext_vector_type(4)));
typedef float floatx4 __attribute__((ext_vector_type(4)));

__device__ __forceinline__ float b2f(unsigned short u) {
  union { float f; unsigned int i; } x; x.i = ((unsigned int)u) << 16; return x.f;
}
__device__ __forceinline__ unsigned short f2b(float f) {
  union { float f; unsigned int i; } x; x.f = f;
  unsigned int r = x.i + 0x7fffu + ((x.i >> 16) & 1u);
  return (unsigned short)(r >> 16);
}

__device__ __forceinline__ void gload16(const void* g, void* l) {
  __builtin_amdgcn_global_load_lds(
      (__attribute__((address_space(1))) void*)(void*)(g),
      (__attribute__((address_space(3))) void*)(l), 16, 0, 0);
}

__device__ __forceinline__ void wgbar() {
  asm volatile("" ::: "memory");
  __builtin_amdgcn_s_barrier();
  asm volatile("" ::: "memory");
}
#define VMCNT4 asm volatile("s_waitcnt vmcnt(4)" ::: "memory")
#define VMCNT3 asm volatile("s_waitcnt vmcnt(3)" ::: "memory")
#define VMCNT2 asm volatile("s_waitcnt vmcnt(2)" ::: "memory")
#define VMCNT0 asm volatile("s_waitcnt vmcnt(0)" ::: "memory")

__device__ __forceinline__ unsigned cvtpk(float lo, float hi_) {
  unsigned r;
  asm("v_cvt_pk_bf16_f32 %0, %1, %2" : "=v"(r) : "v"(lo), "v"(hi_));
  return r;
}
__device__ __forceinline__ void plswap(unsigned& x, unsigned& y) {
  asm volatile("v_permlane32_swap_b32 %0, %1" : "+v"(x), "+v"(y));
}

// ---------------- fused prep: hs cast + Wq|Wk|Wv transpose-cast + Wo transpose-cast -----
__global__ __launch_bounds__(256) void prepAll(const float* __restrict__ hs,
                                               const float* __restrict__ Wq,
                                               const float* __restrict__ Wk,
                                               const float* __restrict__ Wv,
                                               const float* __restrict__ Wo,
                                               unsigned short* __restrict__ hsb,
                                               unsigned short* __restrict__ Wt,
                                               unsigned short* __restrict__ WoT) {
  __shared__ float t[64][65];
  int tid = threadIdx.x;
  int idx = blockIdx.x;
  if (idx >= 2560) {
    int i = (idx - 2560) * 256 + tid;
    const floatx4* in4 = (const floatx4*)hs;
    floatx4 v0 = in4[(size_t)i * 2], v1 = in4[(size_t)i * 2 + 1];
    ushortx8 o;
    o[0] = f2b(v0.x); o[1] = f2b(v0.y); o[2] = f2b(v0.z); o[3] = f2b(v0.w);
    o[4] = f2b(v1.x); o[5] = f2b(v1.y); o[6] = f2b(v1.z); o[7] = f2b(v1.w);
    ((ushortx8*)hsb)[i] = o;
    return;
  }
  const float* W; int N, n0, k0; unsigned short* dst;
  if (idx < 1536) {
    int bx = idx % 48, by = idx / 48;
    k0 = by * 64;
    if (bx < 32)      { W = Wq; N = 2048; n0 = bx * 64;        dst = Wt; }
    else if (bx < 40) { W = Wk; N = 512;  n0 = (bx - 32) * 64; dst = Wt + (size_t)2048 * 2048; }
    else              { W = Wv; N = 512;  n0 = (bx - 40) * 64; dst = Wt + (size_t)2560 * 2048; }
  } else {
    int id2 = idx - 1536;
    W = Wo; N = 2048; n0 = (id2 & 31) * 64; k0 = (id2 >> 5) * 64;
    dst = WoT;
  }
#pragma unroll
  for (int u0 = 0; u0 < 1024; u0 += 256) {
    int u = u0 + tid;
    int r = u >> 4, c4 = (u & 15) * 4;
    floatx4 v = *(const floatx4*)(const void*)&W[(size_t)(k0 + r) * N + n0 + c4];
    t[r][c4 + 0] = v.x; t[r][c4 + 1] = v.y; t[r][c4 + 2] = v.z; t[r][c4 + 3] = v.w;
  }
  __syncthreads();
#pragma unroll
  for (int u0 = 0; u0 < 512; u0 += 256) {
    int u = u0 + tid;
    int n = u >> 3, g = (u & 7) * 8;
    ushortx8 o;
#pragma unroll
    for (int k2 = 0; k2 < 8; ++k2) o[k2] = f2b(t[g + k2][n]);
    *(ushortx8*)(void*)&dst[(size_t)(n0 + n) * HID + k0 + g] = o;
  }
}

// ---------------- GEMM 128x192 tile, BK=64, 8 waves (2M x 4N), 2-phase/K-tile (QKV) ----
// A-fragments for BOTH kf hoisted into Ph1 (buf[cur] stable across phases) so Ph2's
// MFMA cluster has no ds_read latency in front of it.
template <int BF16OUT>
__global__ __launch_bounds__(512, 2) void gemmQ(const unsigned short* __restrict__ A,
                                                const unsigned short* __restrict__ Bt,
                                                void* __restrict__ Cv, int M, int N, int K) {
  __shared__ __align__(16) unsigned char smem[81920];   // 2 x (A 16K + B 24K)
  const int tid = threadIdx.x;
  const int wave = tid >> 6, lane = tid & 63;
  const int fr = lane & 15, fq = lane >> 4;
  const int wm = wave & 1, wn = wave >> 1;

  const int xcd = blockIdx.x & 7, inr = blockIdx.x >> 3;
  const int mt = (xcd >> 1) * 8 + (inr >> 3);     // 0..31
  const int ntt = (xcd & 1) * 8 + (inr & 7);      // 0..15
  const int m0 = mt << 7, n0 = ntt * 192;
  const int NT = K >> 6;

  const int l8 = lane >> 3, l7 = lane & 7;
  const size_t srcOff = (size_t)(wave * 8 + l8) * K + ((l7 ^ l8) * 8);
  const unsigned short* Ag = A + (size_t)m0 * K;
  const unsigned short* Bg = Bt + (size_t)n0 * K;

  const int cx0 = (fq * 16) ^ ((fr & 7) << 4);
  const int cx1 = (64 + fq * 16) ^ ((fr & 7) << 4);
  const int aRowB = (wm * 64 + fr) * 128;
  const int bRowB = (wn * 48 + fr) * 128;

#define SA(kt2)  { const unsigned short* gp = Ag + (size_t)(kt2) * 64 + srcOff;             \
    char* lp = (char*)smem + (((kt2) & 1) * 40960) + wave * 1024;                           \
    gload16(gp, lp);  gload16(gp + (size_t)64 * K, lp + 8192); }
#define SB(kt2)  { const unsigned short* gp = Bg + (size_t)(kt2) * 64 + srcOff;             \
    char* lp = (char*)smem + (((kt2) & 1) * 40960) + 16384 + wave * 1024;                   \
    gload16(gp, lp);  gload16(gp + (size_t)64 * K, lp + 8192);                              \
    gload16(gp + (size_t)128 * K, lp + 16384); }

  f32x4 acc[4][3] = {};
  bf16x8 aF0[4], aF1[4], bF[3][2];

#define LDAB { const char* b_ = (const char*)smem + cur * 40960 + aRowB;                    \
    _Pragma("unroll") for (int mi = 0; mi < 4; ++mi) {                                      \
      aF0[mi] = *(const bf16x8*)(const void*)(b_ + mi * 2048 + cx0);                        \
      aF1[mi] = *(const bf16x8*)(const void*)(b_ + mi * 2048 + cx1); }                      \
    const char* c_ = (const char*)smem + cur * 40960 + 16384 + bRowB;                       \
    _Pragma("unroll") for (int ni = 0; ni < 3; ++ni) {                                      \
      bF[ni][0] = *(const bf16x8*)(const void*)(c_ + ni * 2048 + cx0);                      \
      bF[ni][1] = *(const bf16x8*)(const void*)(c_ + ni * 2048 + cx1); } }
#define MM12(AF, kf) { __builtin_amdgcn_s_setprio(1);                                       \
    _Pragma("unroll") for (int mi = 0; mi < 4; ++mi)                                        \
    _Pragma("unroll") for (int ni = 0; ni < 3; ++ni)                                        \
      acc[mi][ni] = __builtin_amdgcn_mfma_f32_16x16x32_bf16(                                \
          AF[mi], bF[ni][kf], acc[mi][ni], 0, 0, 0);                                        \
    __builtin_amdgcn_s_setprio(0); }

  SA(0); SB(0); SB(1);
  VMCNT3;
  wgbar();

  for (int kt = 0; kt < NT; ++kt) {
    const int cur = kt & 1;
    LDAB;
    if (kt + 1 < NT) SA(kt + 1);
    wgbar();
    MM12(aF0, 0);
    wgbar();
    if (kt + 2 < NT) { SB(kt + 2); VMCNT3; }
    else if (kt + 1 < NT) { VMCNT0; }
    wgbar();
    MM12(aF1, 1);
    wgbar();
  }

#pragma unroll
  for (int mi = 0; mi < 4; ++mi)
#pragma unroll
    for (int ni = 0; ni < 3; ++ni)
#pragma unroll
      for (int r = 0; r < 4; ++r) {
        size_t row = (size_t)(m0 + wm * 64 + mi * 16 + fq * 4 + r);
        size_t col = (size_t)(n0 + wn * 48 + ni * 16 + fr);
        if (BF16OUT)
          ((unsigned short*)Cv)[row * N + col] = f2b(acc[mi][ni][r]);
        else
          ((float*)Cv)[row * N + col] = acc[mi][ni][r];
      }
#undef SA
#undef SB
#undef LDAB
#undef MM12
}

// ---------------- GEMM 128x128 tile, BK=64, 8 waves (2M x 4N), 2-phase/K-tile (Wo) ------
template <int BF16OUT>
__global__ __launch_bounds__(512, 2) void gemmO(const unsigned short* __restrict__ A,
                                                const unsigned short* __restrict__ Bt,
                                                void* __restrict__ Cv, int M, int N, int K) {
  __shared__ __align__(16) unsigned char smem[65536];   // 2 x (A 16K + B 16K)
  const int tid = threadIdx.x;
  const int wave = tid >> 6, lane = tid & 63;
  const int fr = lane & 15, fq = lane >> 4;
  const int wm = wave & 1, wn = wave >> 1;

  const int xcd = blockIdx.x & 7, inr = blockIdx.x >> 3;
  const int mt = (xcd >> 1) * 8 + (inr >> 3);     // 0..31
  const int ntt = (xcd & 1) * 8 + (inr & 7);      // 0..15
  const int m0 = mt << 7, n0 = ntt << 7;
  const int NT = K >> 6;

  const int l8 = lane >> 3, l7 = lane & 7;
  const size_t srcOff = (size_t)(wave * 8 + l8) * K + ((l7 ^ l8) * 8);
  const unsigned short* Ag = A + (size_t)m0 * K;
  const unsigned short* Bg = Bt + (size_t)n0 * K;

  const int cx0 = (fq * 16) ^ ((fr & 7) << 4);
  const int cx1 = (64 + fq * 16) ^ ((fr & 7) << 4);
  const int aRowB = (wm * 64 + fr) * 128;
  const int bRowB = (wn * 32 + fr) * 128;

#define SA(kt2)  { const unsigned short* gp = Ag + (size_t)(kt2) * 64 + srcOff;             \
    char* lp = (char*)smem + (((kt2) & 1) * 32768) + wave * 1024;                           \
    gload16(gp, lp);  gload16(gp + (size_t)64 * K, lp + 8192); }
#define SB(kt2)  { const unsigned short* gp = Bg + (size_t)(kt2) * 64 + srcOff;             \
    char* lp = (char*)smem + (((kt2) & 1) * 32768) + 16384 + wave * 1024;                   \
    gload16(gp, lp);  gload16(gp + (size_t)64 * K, lp + 8192); }

  f32x4 acc[4][2] = {};
  bf16x8 aF0[4], aF1[4], bF[2][2];

#define LDAB { const char* b_ = (const char*)smem + cur * 32768 + aRowB;                    \
    _Pragma("unroll") for (int mi = 0; mi < 4; ++mi) {                                      \
      aF0[mi] = *(const bf16x8*)(const void*)(b_ + mi * 2048 + cx0);                        \
      aF1[mi] = *(const bf16x8*)(const void*)(b_ + mi * 2048 + cx1); }                      \
    const char* c_ = (const char*)smem + cur * 32768 + 16384 + bRowB;                       \
    _Pragma("unroll") for (int ni = 0; ni < 2; ++ni) {                                      \
      bF[ni][0] = *(const bf16x8*)(const void*)(c_ + ni * 2048 + cx0);                      \
      bF[ni][1] = *(const bf16x8*)(const void*)(c_ + ni * 2048 + cx1); } }
#define MM8(AF, kf) { __builtin_amdgcn_s_setprio(1);                                        \
    _Pragma("unroll") for (int mi = 0; mi < 4; ++mi)                                        \
    _Pragma("unroll") for (int ni = 0; ni < 2; ++ni)                                        \
      acc[mi][ni] = __builtin_amdgcn_mfma_f32_16x16x32_bf16(                                \
          AF[mi], bF[ni][kf], acc[mi][ni], 0, 0, 0);                                        \
    __builtin_amdgcn_s_setprio(0); }

  SA(0); SB(0); SB(1);
  VMCNT2;
  wgbar();

  for (int kt = 0; kt < NT; ++kt) {
    const int cur = kt & 1;
    LDAB;
    if (kt + 1 < NT) SA(kt + 1);
    wgbar();
    MM8(aF0, 0);
    wgbar();
    if (kt + 2 < NT) { SB(kt + 2); VMCNT2; }
    else if (kt + 1 < NT) { VMCNT0; }
    wgbar();
    MM8(aF1, 1);
    wgbar();
  }

#pragma unroll
  for (int mi = 0; mi < 4; ++mi)
#pragma unroll
    for (int ni = 0; ni < 2; ++ni)
#pragma unroll
      for (int r = 0; r < 4; ++r) {
        size_t row = (size_t)(m0 + wm * 64 + mi * 16 + fq * 4 + r);
        size_t col = (size_t)(n0 + wn * 32 + ni * 16 + fr);
        if (BF16OUT)
          ((unsigned short*)Cv)[row * N + col] = f2b(acc[mi][ni][r]);
        else
          ((float*)Cv)[row * N + col] = acc[mi][ni][r];
      }
#undef SA
#undef SB
#undef LDAB
#undef MM8
}

// ---------------- fused RoPE (QKV Q/K cols) + V transpose (QKV V cols -> Vt) -----------
__global__ __launch_bounds__(256) void ropeVtrans(unsigned short* __restrict__ QKV,
                                                  const int* __restrict__ pos,
                                                  unsigned short* __restrict__ Vt) {
  int t = threadIdx.x;
  if (blockIdx.x < ROWS) {
    int bs = blockIdx.x;
    __shared__ float cs[64], sn[64];
    if (t < 64) {
      float p = (float)pos[bs];
      float inv = expf(-(float)t * 0.14391156831212787f);
      sincosf(p * inv, &sn[t], &cs[t]);
    }
    __syncthreads();
    unsigned short* row = QKV + (size_t)bs * NQKV;
    if (t < 160) {
      int h = t >> 3, d0 = (t & 7) * 8;
      int col = (h < 16) ? h * DH : KOFF + (h - 16) * DH;
      float sc = (h < 16) ? 0.08838834764831845f : 1.0f;
      ushortx8 lo = *(const ushortx8*)(const void*)(row + col + d0);
      ushortx8 hi = *(const ushortx8*)(const void*)(row + col + 64 + d0);
      ushortx8 olo, ohi;
#pragma unroll
      for (int k = 0; k < 8; ++k) {
        float x1 = b2f(lo[k]), x2 = b2f(hi[k]);
        float c = cs[d0 + k], s = sn[d0 + k];
        olo[k] = f2b((x1 * c - x2 * s) * sc);
        ohi[k] = f2b((x2 * c + x1 * s) * sc);
      }
      *(ushortx8*)(void*)(row + col + d0) = olo;
      *(ushortx8*)(void*)(row + col + 64 + d0) = ohi;
    }
  } else {
    int id2 = blockIdx.x - ROWS;            // 0..2047
    __shared__ unsigned short tl[32][34];
    int s0 = (id2 & 63) * 32;
    int d0 = ((id2 >> 6) & 3) * 32;
    int bh = id2 >> 8;                      // 0..7
    int b = bh >> 2, h = bh & 3;
    int tx = t & 31, ty = t >> 5;
    const unsigned short* src = QKV + (size_t)b * SS * NQKV + VOFF + h * DH;
    for (int i = 0; i < 32; i += 8)
      tl[ty + i][tx] = src[(size_t)(s0 + ty + i) * NQKV + d0 + tx];
    __syncthreads();
    unsigned short* dst = Vt + ((size_t)(b * NKV + h) * DH) * SS;
    for (int i = 0; i < 32; i += 8)
      dst[(size_t)(d0 + ty + i) * SS + s0 + tx] = tl[tx][ty + i];
  }
}

// ---------------- flash attention: 8 waves, wave = 32q x 32kv quadrant (kv-split) -------
// r18/r20 kernel (58.3-58.5us best, conflicts=0).
__global__ __launch_bounds__(512, 2) void attn_kernel(const unsigned short* __restrict__ QKV,
                                                      const unsigned short* __restrict__ Vt,
                                                      unsigned short* __restrict__ Out) {
  int id = blockIdx.x;
  int g = id & 7;
  int b = g >> 2, hkv = g & 3;
  int r3 = id >> 3;
  int hsub = (r3 >> 2) & 3;
  int h = hkv * 4 + hsub;
  int q0 = (r3 & 3) | (((r3 >> 4) & 1) << 2);
  int qt = (r3 >> 5) ? (15 - q0) : q0;   // bit-5 reflection -> balanced CU pairs
  int tid = threadIdx.x;
  int w = tid >> 6, lane = tid & 63;
  int l31 = lane & 31, hi = lane >> 5;
  int qw = w & 3, kh = w >> 2;

  __shared__ __align__(16) char smem[66560];
  float* lsumA = (float*)(void*)(smem + 65536);

  const unsigned short* Kbase = QKV + (size_t)b * SS * NQKV + KOFF + hkv * DH;
  const unsigned short* Vbase = Vt + (size_t)(b * NKV + hkv) * DH * SS;

  int kr4 = lane >> 4, kc = lane & 15;   // K staging: 4 rows / gload16
  int vr8 = lane >> 3, vc = lane & 7;    // V staging: 8 rows / gload16

#define STAGE(kv0, buf)                                                                  \
  { _Pragma("unroll") for (int i = 0; i < 2; ++i) {                                      \
      int r0 = w * 8 + i * 4; int row = r0 + kr4;                                        \
      gload16(Kbase + (size_t)((kv0) + row) * NQKV + ((kc ^ (row & 15)) * 8),            \
              smem + (buf) * 16384 + r0 * 256); }                                        \
    _Pragma("unroll") for (int i = 0; i < 2; ++i) {                                      \
      int r0 = w * 16 + i * 8; int row = r0 + vr8;                                       \
      gload16(Vbase + (size_t)row * SS + (kv0) + ((vc ^ ((row ^ (row >> 3)) & 7)) * 8),  \
              smem + 32768 + (buf) * 16384 + r0 * 128); } }

  const unsigned short* Qp =
      QKV + (size_t)((size_t)b * SS + qt * 128 + qw * 32 + l31) * NQKV + h * DH + hi * 8;
  bf16x8 qf[8];
#pragma unroll
  for (int ks = 0; ks < 8; ++ks) qf[ks] = *(const bf16x8*)(const void*)(Qp + ks * 16);

  f32x16 o[4] = {};
  float lsum = 0.f;
  int nt = 2 * qt + 2;
  int krd = kh * 32 + l31;                 // K row this lane reads
  int kswz = (krd & 15) << 4;
  STAGE(0, 0);
  VMCNT0;
  wgbar();
  int cur = 0;

  for (int t = 0; t < nt; ++t) {
    if (t + 1 < nt) STAGE((t + 1) * 64, cur ^ 1);

    // S^T = K Q : this wave's kv block (kh)
    f32x16 s0 = {};
    {
      const char* kb = smem + cur * 16384 + krd * 256;
      __builtin_amdgcn_s_setprio(1);
#pragma unroll
      for (int ks = 0; ks < 8; ++ks) {
        bf16x8 k0 = *(const bf16x8*)(const void*)(kb + ((ks * 32 + hi * 16) ^ kswz));
        s0 = __builtin_amdgcn_mfma_f32_32x32x16_bf16(k0, qf[ks], s0, 0, 0, 0);
      }
      __builtin_amdgcn_s_setprio(0);
    }

    // fixed-max softmax; lane owns q-col l31; reg r -> kv row (r&3)+8*(r>>2)+4*hi +32*kh
    float p0[16];
    float ps = 0.f;
    if (t >= 2 * qt) {
      int qrel = qw * 32 + l31 - (t - 2 * qt) * 64;
#pragma unroll
      for (int r = 0; r < 16; ++r) {
        int kvr = (r & 3) + 8 * (r >> 2) + 4 * hi + 32 * kh;
        float e0 = __expf(s0[r]);
        p0[r] = (kvr <= qrel) ? e0 : 0.f;
        ps += p0[r];
      }
    } else {
#pragma unroll
      for (int r = 0; r < 16; ++r) { p0[r] = __expf(s0[r]); ps += p0[r]; }
    }
    lsum += ps;

    // pack P -> PV A-fragments (cvt_pk + permlane32_swap)
    union U8 { unsigned u[4]; bf16x8 v; } fa[2];
    {
      unsigned a0 = cvtpk(p0[0], p0[1]),  a1 = cvtpk(p0[2], p0[3]);
      unsigned a2 = cvtpk(p0[4], p0[5]),  a3 = cvtpk(p0[6], p0[7]);
      plswap(a0, a2); plswap(a1, a3);
      fa[0].u[0] = a0; fa[0].u[1] = a1; fa[0].u[2] = a2; fa[0].u[3] = a3;
      unsigned a4 = cvtpk(p0[8], p0[9]),   a5 = cvtpk(p0[10], p0[11]);
      unsigned a6 = cvtpk(p0[12], p0[13]), a7 = cvtpk(p0[14], p0[15]);
      plswap(a4, a6); plswap(a5, a7);
      fa[1].u[0] = a4; fa[1].u[1] = a5; fa[1].u[2] = a6; fa[1].u[3] = a7;
    }

    // O += P V over this wave's 32 kv (k = kh*32 + ks*16 + hi*8 + j)
    __builtin_amdgcn_s_setprio(1);
#pragma unroll
    for (int dblk = 0; dblk < 4; ++dblk) {
      int vrd = dblk * 32 + l31;            // V row (d) this lane reads
      int vswz = ((vrd ^ (vrd >> 3)) & 7) << 4;
      const char* vrow = smem + 32768 + cur * 16384 + vrd * 128;
#pragma unroll
      for (int ks = 0; ks < 2; ++ks) {
        bf16x8 vb = *(const bf16x8*)(const void*)(vrow + ((kh * 64 + ks * 32 + hi * 16) ^ vswz));
        o[dblk] = __builtin_amdgcn_mfma_f32_32x32x16_bf16(fa[ks].v, vb, o[dblk], 0, 0, 0);
      }
    }
    __builtin_amdgcn_s_setprio(0);

    VMCNT0;
    wgbar();
    cur ^= 1;
  }
#undef STAGE

  // epilogue: combine hi halves of lsum; kh=1 waves dump O+lsum; kh=0 reduce+write
  float ls = lsum + __shfl_xor(lsum, 32);
  if (hi == 0) lsumA[w * 32 + l31] = ls;
  if (kh == 1) {
    float* rp = (float*)(void*)smem + qw * 4096;   // [32 q][128 d] f32 per qw
#pragma unroll
    for (int r = 0; r < 16; ++r) {
      int qr = (r & 3) + 8 * (r >> 2) + 4 * hi;
#pragma unroll
      for (int dblk = 0; dblk < 4; ++dblk)
        rp[qr * 128 + dblk * 32 + l31] = o[dblk][r];
    }
  }
  __syncthreads();
  if (kh == 0) {
    const float* rp = (const float*)(void*)smem + qw * 4096;
    size_t obase = (size_t)((size_t)b * SS + qt * 128 + qw * 32) * HID + h * DH + l31;
#pragma unroll
    for (int r = 0; r < 16; ++r) {
      int qr = (r & 3) + 8 * (r >> 2) + 4 * hi;
      float tot = lsumA[qw * 32 + qr] + lsumA[(qw + 4) * 32 + qr];
      float inv = 1.0f / tot;
      size_t orow = obase + (size_t)qr * HID;
#pragma unroll
      for (int dblk = 0; dblk < 4; ++dblk)
        Out[orow + dblk * 32] = f2b((o[dblk][r] + rp[qr * 128 + dblk * 32 + l31]) * inv);
    }
  }
}

extern "C" void kernel_launch(void* const* d_in, const int* in_sizes, int n_in,
                              void* d_out, int out_size, void* d_ws, size_t ws_size,
                              hipStream_t stream) {
  const float* hs = (const float*)d_in[0];
  const int* pos = (const int*)d_in[1];
  const float* Wq = (const float*)d_in[2];
  const float* Wk = (const float*)d_in[3];
  const float* Wv = (const float*)d_in[4];
  const float* Wo = (const float*)d_in[5];

  char* ws = (char*)d_ws;
  size_t off = 0;
  unsigned short* hsb = (unsigned short*)(ws + off); off += (size_t)ROWS * HID * 2;   // reused as attn out
  unsigned short* WqkvT = (unsigned short*)(ws + off); off += (size_t)NQKV * HID * 2;
  unsigned short* WoT = (unsigned short*)(ws + off); off += (size_t)HID * HID * 2;
  unsigned short* QKV = (unsigned short*)(ws + off); off += (size_t)ROWS * NQKV * 2;
  unsigned short* Vtb = (unsigned short*)(ws + off); off += (size_t)BB * NKV * DH * SS * 2;

  prepAll<<<6656, 256, 0, stream>>>(hs, Wq, Wk, Wv, Wo, hsb, WqkvT, WoT);

  gemmQ<1><<<(ROWS / 128) * (NQKV / 192), 512, 0, stream>>>(hsb, WqkvT, QKV, ROWS, NQKV, HID);
  ropeVtrans<<<ROWS + 2048, 256, 0, stream>>>(QKV, pos, Vtb);
  attn_kernel<<<512, 512, 0, stream>>>(QKV, Vtb, hsb);
  gemmO<0><<<(ROWS / 128) * (HID / 128), 512, 0, stream>>>(hsb, WoT, d_out, ROWS, HID, HID);
}

// Round 25
// 167.351 us; speedup vs baseline: 1.0179x; 1.0179x over previous
//
#include <hip/hip_runtime.h>
#include <math.h>

#define HID 2048
#define NH 16
#define NKV 4
#define DH 128
#define BB 2
#define SS 2048
#define ROWS (BB*SS)     // 4096
#define NQKV 3072
#define KOFF 2048        // K block col offset in QKV
#define VOFF 2560        // V block col offset in QKV

typedef float f32x4 __attribute__((ext_vector_type(4)));
typedef float f32x16 __attribute__((ext_vector_type(16)));
typedef __bf16 bf16x8 __attribute__((ext_vector_type(8)));
typedef unsigned short ushortx8 __attribute__((ext_vector_type(8)));
typedef unsigned short ushortx4 __attribute__((ext_vector_type(4)));
typedef float floatx4 __attribute__((ext_vector_type(4)));

__device__ __forceinline__ float b2f(unsigned short u) {
  union { float f; unsigned int i; } x; x.i = ((unsigned int)u) << 16; return x.f;
}
__device__ __forceinline__ unsigned short f2b(float f) {
  union { float f; unsigned int i; } x; x.f = f;
  unsigned int r = x.i + 0x7fffu + ((x.i >> 16) & 1u);
  return (unsigned short)(r >> 16);
}

__device__ __forceinline__ void gload16(const void* g, void* l) {
  __builtin_amdgcn_global_load_lds(
      (__attribute__((address_space(1))) void*)(void*)(g),
      (__attribute__((address_space(3))) void*)(l), 16, 0, 0);
}

__device__ __forceinline__ void wgbar() {
  asm volatile("" ::: "memory");
  __builtin_amdgcn_s_barrier();
  asm volatile("" ::: "memory");
}
#define VMCNT4 asm volatile("s_waitcnt vmcnt(4)" ::: "memory")
#define VMCNT3 asm volatile("s_waitcnt vmcnt(3)" ::: "memory")
#define VMCNT2 asm volatile("s_waitcnt vmcnt(2)" ::: "memory")
#define VMCNT0 asm volatile("s_waitcnt vmcnt(0)" ::: "memory")

__device__ __forceinline__ unsigned cvtpk(float lo, float hi_) {
  unsigned r;
  asm("v_cvt_pk_bf16_f32 %0, %1, %2" : "=v"(r) : "v"(lo), "v"(hi_));
  return r;
}
__device__ __forceinline__ void plswap(unsigned& x, unsigned& y) {
  asm volatile("v_permlane32_swap_b32 %0, %1" : "+v"(x), "+v"(y));
}

// ---------------- fused prep: hs cast + Wq|Wk|Wv transpose-cast + Wo transpose-cast -----
__global__ __launch_bounds__(256) void prepAll(const float* __restrict__ hs,
                                               const float* __restrict__ Wq,
                                               const float* __restrict__ Wk,
                                               const float* __restrict__ Wv,
                                               const float* __restrict__ Wo,
                                               unsigned short* __restrict__ hsb,
                                               unsigned short* __restrict__ Wt,
                                               unsigned short* __restrict__ WoT) {
  __shared__ float t[64][65];
  int tid = threadIdx.x;
  int idx = blockIdx.x;
  if (idx >= 2560) {
    int i = (idx - 2560) * 256 + tid;
    const floatx4* in4 = (const floatx4*)hs;
    floatx4 v0 = in4[(size_t)i * 2], v1 = in4[(size_t)i * 2 + 1];
    ushortx8 o;
    o[0] = f2b(v0.x); o[1] = f2b(v0.y); o[2] = f2b(v0.z); o[3] = f2b(v0.w);
    o[4] = f2b(v1.x); o[5] = f2b(v1.y); o[6] = f2b(v1.z); o[7] = f2b(v1.w);
    ((ushortx8*)hsb)[i] = o;
    return;
  }
  const float* W; int N, n0, k0; unsigned short* dst;
  if (idx < 1536) {
    int bx = idx % 48, by = idx / 48;
    k0 = by * 64;
    if (bx < 32)      { W = Wq; N = 2048; n0 = bx * 64;        dst = Wt; }
    else if (bx < 40) { W = Wk; N = 512;  n0 = (bx - 32) * 64; dst = Wt + (size_t)2048 * 2048; }
    else              { W = Wv; N = 512;  n0 = (bx - 40) * 64; dst = Wt + (size_t)2560 * 2048; }
  } else {
    int id2 = idx - 1536;
    W = Wo; N = 2048; n0 = (id2 & 31) * 64; k0 = (id2 >> 5) * 64;
    dst = WoT;
  }
#pragma unroll
  for (int u0 = 0; u0 < 1024; u0 += 256) {
    int u = u0 + tid;
    int r = u >> 4, c4 = (u & 15) * 4;
    floatx4 v = *(const floatx4*)(const void*)&W[(size_t)(k0 + r) * N + n0 + c4];
    t[r][c4 + 0] = v.x; t[r][c4 + 1] = v.y; t[r][c4 + 2] = v.z; t[r][c4 + 3] = v.w;
  }
  __syncthreads();
#pragma unroll
  for (int u0 = 0; u0 < 512; u0 += 256) {
    int u = u0 + tid;
    int n = u >> 3, g = (u & 7) * 8;
    ushortx8 o;
#pragma unroll
    for (int k2 = 0; k2 < 8; ++k2) o[k2] = f2b(t[g + k2][n]);
    *(ushortx8*)(void*)&dst[(size_t)(n0 + n) * HID + k0 + g] = o;
  }
}

// ---------------- GEMM 128x192 tile, BK=64, 8 waves (2M x 4N), 2-phase/K-tile (QKV) ----
// r23-measured-best loop shape: LDA(0)+LDBALL in Ph1, LDA(1) in Ph2 (r24's full A-hoist
// into Ph1 regressed +2.2us: 14-deep pre-barrier ds_read cluster lengthened Ph1).
template <int BF16OUT>
__global__ __launch_bounds__(512, 2) void gemmQ(const unsigned short* __restrict__ A,
                                                const unsigned short* __restrict__ Bt,
                                                void* __restrict__ Cv, int M, int N, int K) {
  __shared__ __align__(16) unsigned char smem[81920];   // 2 x (A 16K + B 24K)
  const int tid = threadIdx.x;
  const int wave = tid >> 6, lane = tid & 63;
  const int fr = lane & 15, fq = lane >> 4;
  const int wm = wave & 1, wn = wave >> 1;

  const int xcd = blockIdx.x & 7, inr = blockIdx.x >> 3;
  const int mt = (xcd >> 1) * 8 + (inr >> 3);     // 0..31
  const int ntt = (xcd & 1) * 8 + (inr & 7);      // 0..15
  const int m0 = mt << 7, n0 = ntt * 192;
  const int NT = K >> 6;

  const int l8 = lane >> 3, l7 = lane & 7;
  const size_t srcOff = (size_t)(wave * 8 + l8) * K + ((l7 ^ l8) * 8);
  const unsigned short* Ag = A + (size_t)m0 * K;
  const unsigned short* Bg = Bt + (size_t)n0 * K;

  const int cx0 = (fq * 16) ^ ((fr & 7) << 4);
  const int cx1 = (64 + fq * 16) ^ ((fr & 7) << 4);
  const int aRowB = (wm * 64 + fr) * 128;
  const int bRowB = (wn * 48 + fr) * 128;

#define SA(kt2)  { const unsigned short* gp = Ag + (size_t)(kt2) * 64 + srcOff;             \
    char* lp = (char*)smem + (((kt2) & 1) * 40960) + wave * 1024;                           \
    gload16(gp, lp);  gload16(gp + (size_t)64 * K, lp + 8192); }
#define SB(kt2)  { const unsigned short* gp = Bg + (size_t)(kt2) * 64 + srcOff;             \
    char* lp = (char*)smem + (((kt2) & 1) * 40960) + 16384 + wave * 1024;                   \
    gload16(gp, lp);  gload16(gp + (size_t)64 * K, lp + 8192);                              \
    gload16(gp + (size_t)128 * K, lp + 16384); }

  f32x4 acc[4][3] = {};
  bf16x8 aF[4], bF[3][2];

#define LDA(kf) { const char* b_ = (const char*)smem + cur * 40960 + aRowB;                 \
    _Pragma("unroll") for (int mi = 0; mi < 4; ++mi)                                        \
      aF[mi] = *(const bf16x8*)(const void*)(b_ + mi * 2048 + ((kf) ? cx1 : cx0)); }
#define LDBALL { const char* b_ = (const char*)smem + cur * 40960 + 16384 + bRowB;          \
    _Pragma("unroll") for (int ni = 0; ni < 3; ++ni) {                                      \
      bF[ni][0] = *(const bf16x8*)(const void*)(b_ + ni * 2048 + cx0);                      \
      bF[ni][1] = *(const bf16x8*)(const void*)(b_ + ni * 2048 + cx1); } }
#define MM12(kf) { __builtin_amdgcn_s_setprio(1);                                           \
    _Pragma("unroll") for (int mi = 0; mi < 4; ++mi)                                        \
    _Pragma("unroll") for (int ni = 0; ni < 3; ++ni)                                        \
      acc[mi][ni] = __builtin_amdgcn_mfma_f32_16x16x32_bf16(                                \
          aF[mi], bF[ni][kf], acc[mi][ni], 0, 0, 0);                                        \
    __builtin_amdgcn_s_setprio(0); }

  SA(0); SB(0); SB(1);
  VMCNT3;
  wgbar();

  for (int kt = 0; kt < NT; ++kt) {
    const int cur = kt & 1;
    LDA(0); LDBALL;
    if (kt + 1 < NT) SA(kt + 1);
    wgbar();
    MM12(0);
    wgbar();
    LDA(1);
    if (kt + 2 < NT) { SB(kt + 2); VMCNT3; }
    else if (kt + 1 < NT) { VMCNT0; }
    wgbar();
    MM12(1);
    wgbar();
  }

#pragma unroll
  for (int mi = 0; mi < 4; ++mi)
#pragma unroll
    for (int ni = 0; ni < 3; ++ni)
#pragma unroll
      for (int r = 0; r < 4; ++r) {
        size_t row = (size_t)(m0 + wm * 64 + mi * 16 + fq * 4 + r);
        size_t col = (size_t)(n0 + wn * 48 + ni * 16 + fr);
        if (BF16OUT)
          ((unsigned short*)Cv)[row * N + col] = f2b(acc[mi][ni][r]);
        else
          ((float*)Cv)[row * N + col] = acc[mi][ni][r];
      }
#undef SA
#undef SB
#undef LDA
#undef LDBALL
#undef MM12
}

// ---------------- GEMM 128x128 tile, BK=64, 8 waves (2M x 4N), 2-phase/K-tile (Wo) ------
template <int BF16OUT>
__global__ __launch_bounds__(512, 2) void gemmO(const unsigned short* __restrict__ A,
                                                const unsigned short* __restrict__ Bt,
                                                void* __restrict__ Cv, int M, int N, int K) {
  __shared__ __align__(16) unsigned char smem[65536];   // 2 x (A 16K + B 16K)
  const int tid = threadIdx.x;
  const int wave = tid >> 6, lane = tid & 63;
  const int fr = lane & 15, fq = lane >> 4;
  const int wm = wave & 1, wn = wave >> 1;

  const int xcd = blockIdx.x & 7, inr = blockIdx.x >> 3;
  const int mt = (xcd >> 1) * 8 + (inr >> 3);     // 0..31
  const int ntt = (xcd & 1) * 8 + (inr & 7);      // 0..15
  const int m0 = mt << 7, n0 = ntt << 7;
  const int NT = K >> 6;

  const int l8 = lane >> 3, l7 = lane & 7;
  const size_t srcOff = (size_t)(wave * 8 + l8) * K + ((l7 ^ l8) * 8);
  const unsigned short* Ag = A + (size_t)m0 * K;
  const unsigned short* Bg = Bt + (size_t)n0 * K;

  const int cx0 = (fq * 16) ^ ((fr & 7) << 4);
  const int cx1 = (64 + fq * 16) ^ ((fr & 7) << 4);
  const int aRowB = (wm * 64 + fr) * 128;
  const int bRowB = (wn * 32 + fr) * 128;

#define SA(kt2)  { const unsigned short* gp = Ag + (size_t)(kt2) * 64 + srcOff;             \
    char* lp = (char*)smem + (((kt2) & 1) * 32768) + wave * 1024;                           \
    gload16(gp, lp);  gload16(gp + (size_t)64 * K, lp + 8192); }
#define SB(kt2)  { const unsigned short* gp = Bg + (size_t)(kt2) * 64 + srcOff;             \
    char* lp = (char*)smem + (((kt2) & 1) * 32768) + 16384 + wave * 1024;                   \
    gload16(gp, lp);  gload16(gp + (size_t)64 * K, lp + 8192); }

  f32x4 acc[4][2] = {};
  bf16x8 aF[4], bF[2][2];

#define LDA(kf) { const char* b_ = (const char*)smem + cur * 32768 + aRowB;                 \
    _Pragma("unroll") for (int mi = 0; mi < 4; ++mi)                                        \
      aF[mi] = *(const bf16x8*)(const void*)(b_ + mi * 2048 + ((kf) ? cx1 : cx0)); }
#define LDBALL { const char* b_ = (const char*)smem + cur * 32768 + 16384 + bRowB;          \
    _Pragma("unroll") for (int ni = 0; ni < 2; ++ni) {                                      \
      bF[ni][0] = *(const bf16x8*)(const void*)(b_ + ni * 2048 + cx0);                      \
      bF[ni][1] = *(const bf16x8*)(const void*)(b_ + ni * 2048 + cx1); } }
#define MM8(kf) { __builtin_amdgcn_s_setprio(1);                                            \
    _Pragma("unroll") for (int mi = 0; mi < 4; ++mi)                                        \
    _Pragma("unroll") for (int ni = 0; ni < 2; ++ni)                                        \
      acc[mi][ni] = __builtin_amdgcn_mfma_f32_16x16x32_bf16(                                \
          aF[mi], bF[ni][kf], acc[mi][ni], 0, 0, 0);                                        \
    __builtin_amdgcn_s_setprio(0); }

  SA(0); SB(0); SB(1);
  VMCNT2;
  wgbar();

  for (int kt = 0; kt < NT; ++kt) {
    const int cur = kt & 1;
    LDA(0); LDBALL;
    if (kt + 1 < NT) SA(kt + 1);
    wgbar();
    MM8(0);
    wgbar();
    LDA(1);
    if (kt + 2 < NT) { SB(kt + 2); VMCNT2; }
    else if (kt + 1 < NT) { VMCNT0; }
    wgbar();
    MM8(1);
    wgbar();
  }

#pragma unroll
  for (int mi = 0; mi < 4; ++mi)
#pragma unroll
    for (int ni = 0; ni < 2; ++ni)
#pragma unroll
      for (int r = 0; r < 4; ++r) {
        size_t row = (size_t)(m0 + wm * 64 + mi * 16 + fq * 4 + r);
        size_t col = (size_t)(n0 + wn * 32 + ni * 16 + fr);
        if (BF16OUT)
          ((unsigned short*)Cv)[row * N + col] = f2b(acc[mi][ni][r]);
        else
          ((float*)Cv)[row * N + col] = acc[mi][ni][r];
      }
#undef SA
#undef SB
#undef LDA
#undef LDBALL
#undef MM8
}

// ---------------- fused RoPE (QKV Q/K cols) + V transpose (QKV V cols -> Vt) -----------
__global__ __launch_bounds__(256) void ropeVtrans(unsigned short* __restrict__ QKV,
                                                  const int* __restrict__ pos,
                                                  unsigned short* __restrict__ Vt) {
  int t = threadIdx.x;
  if (blockIdx.x < ROWS) {
    int bs = blockIdx.x;
    __shared__ float cs[64], sn[64];
    if (t < 64) {
      float p = (float)pos[bs];
      float inv = expf(-(float)t * 0.14391156831212787f);
      sincosf(p * inv, &sn[t], &cs[t]);
    }
    __syncthreads();
    unsigned short* row = QKV + (size_t)bs * NQKV;
    if (t < 160) {
      int h = t >> 3, d0 = (t & 7) * 8;
      int col = (h < 16) ? h * DH : KOFF + (h - 16) * DH;
      float sc = (h < 16) ? 0.08838834764831845f : 1.0f;
      ushortx8 lo = *(const ushortx8*)(const void*)(row + col + d0);
      ushortx8 hi = *(const ushortx8*)(const void*)(row + col + 64 + d0);
      ushortx8 olo, ohi;
#pragma unroll
      for (int k = 0; k < 8; ++k) {
        float x1 = b2f(lo[k]), x2 = b2f(hi[k]);
        float c = cs[d0 + k], s = sn[d0 + k];
        olo[k] = f2b((x1 * c - x2 * s) * sc);
        ohi[k] = f2b((x2 * c + x1 * s) * sc);
      }
      *(ushortx8*)(void*)(row + col + d0) = olo;
      *(ushortx8*)(void*)(row + col + 64 + d0) = ohi;
    }
  } else {
    int id2 = blockIdx.x - ROWS;            // 0..2047
    __shared__ unsigned short tl[32][34];
    int s0 = (id2 & 63) * 32;
    int d0 = ((id2 >> 6) & 3) * 32;
    int bh = id2 >> 8;                      // 0..7
    int b = bh >> 2, h = bh & 3;
    int tx = t & 31, ty = t >> 5;
    const unsigned short* src = QKV + (size_t)b * SS * NQKV + VOFF + h * DH;
    for (int i = 0; i < 32; i += 8)
      tl[ty + i][tx] = src[(size_t)(s0 + ty + i) * NQKV + d0 + tx];
    __syncthreads();
    unsigned short* dst = Vt + ((size_t)(b * NKV + h) * DH) * SS;
    for (int i = 0; i < 32; i += 8)
      dst[(size_t)(d0 + ty + i) * SS + s0 + tx] = tl[tx][ty + i];
  }
}

// ---------------- flash attention: 8 waves, wave = 32q x 32kv quadrant (kv-split) -------
// r18/r20 kernel (58.3-58.5us best, conflicts=0).
__global__ __launch_bounds__(512, 2) void attn_kernel(const unsigned short* __restrict__ QKV,
                                                      const unsigned short* __restrict__ Vt,
                                                      unsigned short* __restrict__ Out) {
  int id = blockIdx.x;
  int g = id & 7;
  int b = g >> 2, hkv = g & 3;
  int r3 = id >> 3;
  int hsub = (r3 >> 2) & 3;
  int h = hkv * 4 + hsub;
  int q0 = (r3 & 3) | (((r3 >> 4) & 1) << 2);
  int qt = (r3 >> 5) ? (15 - q0) : q0;   // bit-5 reflection -> balanced CU pairs
  int tid = threadIdx.x;
  int w = tid >> 6, lane = tid & 63;
  int l31 = lane & 31, hi = lane >> 5;
  int qw = w & 3, kh = w >> 2;

  __shared__ __align__(16) char smem[66560];
  float* lsumA = (float*)(void*)(smem + 65536);

  const unsigned short* Kbase = QKV + (size_t)b * SS * NQKV + KOFF + hkv * DH;
  const unsigned short* Vbase = Vt + (size_t)(b * NKV + hkv) * DH * SS;

  int kr4 = lane >> 4, kc = lane & 15;   // K staging: 4 rows / gload16
  int vr8 = lane >> 3, vc = lane & 7;    // V staging: 8 rows / gload16

#define STAGE(kv0, buf)                                                                  \
  { _Pragma("unroll") for (int i = 0; i < 2; ++i) {                                      \
      int r0 = w * 8 + i * 4; int row = r0 + kr4;                                        \
      gload16(Kbase + (size_t)((kv0) + row) * NQKV + ((kc ^ (row & 15)) * 8),            \
              smem + (buf) * 16384 + r0 * 256); }                                        \
    _Pragma("unroll") for (int i = 0; i < 2; ++i) {                                      \
      int r0 = w * 16 + i * 8; int row = r0 + vr8;                                       \
      gload16(Vbase + (size_t)row * SS + (kv0) + ((vc ^ ((row ^ (row >> 3)) & 7)) * 8),  \
              smem + 32768 + (buf) * 16384 + r0 * 128); } }

  const unsigned short* Qp =
      QKV + (size_t)((size_t)b * SS + qt * 128 + qw * 32 + l31) * NQKV + h * DH + hi * 8;
  bf16x8 qf[8];
#pragma unroll
  for (int ks = 0; ks < 8; ++ks) qf[ks] = *(const bf16x8*)(const void*)(Qp + ks * 16);

  f32x16 o[4] = {};
  float lsum = 0.f;
  int nt = 2 * qt + 2;
  int krd = kh * 32 + l31;                 // K row this lane reads
  int kswz = (krd & 15) << 4;
  STAGE(0, 0);
  VMCNT0;
  wgbar();
  int cur = 0;

  for (int t = 0; t < nt; ++t) {
    if (t + 1 < nt) STAGE((t + 1) * 64, cur ^ 1);

    // S^T = K Q : this wave's kv block (kh)
    f32x16 s0 = {};
    {
      const char* kb = smem + cur * 16384 + krd * 256;
      __builtin_amdgcn_s_setprio(1);
#pragma unroll
      for (int ks = 0; ks < 8; ++ks) {
        bf16x8 k0 = *(const bf16x8*)(const void*)(kb + ((ks * 32 + hi * 16) ^ kswz));
        s0 = __builtin_amdgcn_mfma_f32_32x32x16_bf16(k0, qf[ks], s0, 0, 0, 0);
      }
      __builtin_amdgcn_s_setprio(0);
    }

    // fixed-max softmax; lane owns q-col l31; reg r -> kv row (r&3)+8*(r>>2)+4*hi +32*kh
    float p0[16];
    float ps = 0.f;
    if (t >= 2 * qt) {
      int qrel = qw * 32 + l31 - (t - 2 * qt) * 64;
#pragma unroll
      for (int r = 0; r < 16; ++r) {
        int kvr = (r & 3) + 8 * (r >> 2) + 4 * hi + 32 * kh;
        float e0 = __expf(s0[r]);
        p0[r] = (kvr <= qrel) ? e0 : 0.f;
        ps += p0[r];
      }
    } else {
#pragma unroll
      for (int r = 0; r < 16; ++r) { p0[r] = __expf(s0[r]); ps += p0[r]; }
    }
    lsum += ps;

    // pack P -> PV A-fragments (cvt_pk + permlane32_swap)
    union U8 { unsigned u[4]; bf16x8 v; } fa[2];
    {
      unsigned a0 = cvtpk(p0[0], p0[1]),  a1 = cvtpk(p0[2], p0[3]);
      unsigned a2 = cvtpk(p0[4], p0[5]),  a3 = cvtpk(p0[6], p0[7]);
      plswap(a0, a2); plswap(a1, a3);
      fa[0].u[0] = a0; fa[0].u[1] = a1; fa[0].u[2] = a2; fa[0].u[3] = a3;
      unsigned a4 = cvtpk(p0[8], p0[9]),   a5 = cvtpk(p0[10], p0[11]);
      unsigned a6 = cvtpk(p0[12], p0[13]), a7 = cvtpk(p0[14], p0[15]);
      plswap(a4, a6); plswap(a5, a7);
      fa[1].u[0] = a4; fa[1].u[1] = a5; fa[1].u[2] = a6; fa[1].u[3] = a7;
    }

    // O += P V over this wave's 32 kv (k = kh*32 + ks*16 + hi*8 + j)
    __builtin_amdgcn_s_setprio(1);
#pragma unroll
    for (int dblk = 0; dblk < 4; ++dblk) {
      int vrd = dblk * 32 + l31;            // V row (d) this lane reads
      int vswz = ((vrd ^ (vrd >> 3)) & 7) << 4;
      const char* vrow = smem + 32768 + cur * 16384 + vrd * 128;
#pragma unroll
      for (int ks = 0; ks < 2; ++ks) {
        bf16x8 vb = *(const bf16x8*)(const void*)(vrow + ((kh * 64 + ks * 32 + hi * 16) ^ vswz));
        o[dblk] = __builtin_amdgcn_mfma_f32_32x32x16_bf16(fa[ks].v, vb, o[dblk], 0, 0, 0);
      }
    }
    __builtin_amdgcn_s_setprio(0);

    VMCNT0;
    wgbar();
    cur ^= 1;
  }
#undef STAGE

  // epilogue: combine hi halves of lsum; kh=1 waves dump O+lsum; kh=0 reduce+write
  float ls = lsum + __shfl_xor(lsum, 32);
  if (hi == 0) lsumA[w * 32 + l31] = ls;
  if (kh == 1) {
    float* rp = (float*)(void*)smem + qw * 4096;   // [32 q][128 d] f32 per qw
#pragma unroll
    for (int r = 0; r < 16; ++r) {
      int qr = (r & 3) + 8 * (r >> 2) + 4 * hi;
#pragma unroll
      for (int dblk = 0; dblk < 4; ++dblk)
        rp[qr * 128 + dblk * 32 + l31] = o[dblk][r];
    }
  }
  __syncthreads();
  if (kh == 0) {
    const float* rp = (const float*)(void*)smem + qw * 4096;
    size_t obase = (size_t)((size_t)b * SS + qt * 128 + qw * 32) * HID + h * DH + l31;
#pragma unroll
    for (int r = 0; r < 16; ++r) {
      int qr = (r & 3) + 8 * (r >> 2) + 4 * hi;
      float tot = lsumA[qw * 32 + qr] + lsumA[(qw + 4) * 32 + qr];
      float inv = 1.0f / tot;
      size_t orow = obase + (size_t)qr * HID;
#pragma unroll
      for (int dblk = 0; dblk < 4; ++dblk)
        Out[orow + dblk * 32] = f2b((o[dblk][r] + rp[qr * 128 + dblk * 32 + l31]) * inv);
    }
  }
}

extern "C" void kernel_launch(void* const* d_in, const int* in_sizes, int n_in,
                              void* d_out, int out_size, void* d_ws, size_t ws_size,
                              hipStream_t stream) {
  const float* hs = (const float*)d_in[0];
  const int* pos = (const int*)d_in[1];
  const float* Wq = (const float*)d_in[2];
  const float* Wk = (const float*)d_in[3];
  const float* Wv = (const float*)d_in[4];
  const float* Wo = (const float*)d_in[5];

  char* ws = (char*)d_ws;
  size_t off = 0;
  unsigned short* hsb = (unsigned short*)(ws + off); off += (size_t)ROWS * HID * 2;   // reused as attn out
  unsigned short* WqkvT = (unsigned short*)(ws + off); off += (size_t)NQKV * HID * 2;
  unsigned short* WoT = (unsigned short*)(ws + off); off += (size_t)HID * HID * 2;
  unsigned short* QKV = (unsigned short*)(ws + off); off += (size_t)ROWS * NQKV * 2;
  unsigned short* Vtb = (unsigned short*)(ws + off); off += (size_t)BB * NKV * DH * SS * 2;

  prepAll<<<6656, 256, 0, stream>>>(hs, Wq, Wk, Wv, Wo, hsb, WqkvT, WoT);

  gemmQ<1><<<(ROWS / 128) * (NQKV / 192), 512, 0, stream>>>(hsb, WqkvT, QKV, ROWS, NQKV, HID);
  ropeVtrans<<<ROWS + 2048, 256, 0, stream>>>(QKV, pos, Vtb);
  attn_kernel<<<512, 512, 0, stream>>>(QKV, Vtb, hsb);
  gemmO<0><<<(ROWS / 128) * (HID / 128), 512, 0, stream>>>(hsb, WoT, d_out, ROWS, HID, HID);
}